// Round 18
// baseline (174.665 us; speedup 1.0000x reference)
//
#include <hip/hip_runtime.h>

// ConnectivityLoss R30: R24 + manual rotation of X-posts (software pipeline
// WITHOUT unrolling). R29 (full unroll) FAILED: 20MB scratch, 103.5us —
// body duplication stretches A[5] live ranges -> spill (same mode as R28's
// branch dispatch). Lesson: no transformation that duplicates/branches the
// sweep body. Rotation adds NO live values and NO duplication: post rows 0/1
// of next buffer right after UPD(1) (A[0],A[1] final), rows 2/3 after
// UPD(4); iteration top becomes barrier->halo. Write latency hides under
// k=2..4 VALU. Buffer schedule 0,1,0,1,0 per t; t-prologue posts buf0 (after
// t0-stash barrier); epilogue uses BUF1 (last read t1-it3, drained by
// barrier t1-it4) — also fixes R29's latent buf0 race. Bitwise-identical.
// PREDICTION: VGPR 84-92, WRITE ~52KB (MB-scale => revert to R24 final),
// FETCH ~90MB, Occ ~25, dur 96.3 -> 92-95.5us (flat => posts already hidden
// by 3-block TLP => R24 final; structural allocator-cliff limit).
// Knob map (final): (256,3)=84VGPR/no-spill/3blk best; w=4/no-attr = 64VGPR
// squeeze + 50MB spill. R15 LDS diet + R14 min3/max3 kept.

#define IMG 512
#define OC  40            // output cols per tile (13 x-tiles; last partial)
#define TH  128           // output rows per tile (4 y-tiles)
#define TPI 52            // tiles per image = 13 * 4
#define SKW 50            // pred stash cols: pc in [7,56] -> idx pc-7
#define SKH 132           // pred stash rows: pr in [10,141] -> idx pr-10
#define XR   68           // exchange row stride (floats)
#define XSLOT (4*XR)      // 4 rows per wave
#define XHALF (4*XSLOT)   // 4 waves
#define NT  256

struct alignas(16) R8 { float v[8]; };

__device__ __forceinline__ float f3min(float a, float b, float c) {
    float d;
    asm("v_min3_f32 %0, %1, %2, %3" : "=v"(d) : "v"(a), "v"(b), "v"(c));
    return d;
}
__device__ __forceinline__ float f3max(float a, float b, float c) {
    float d;
    asm("v_max3_f32 %0, %1, %2, %3" : "=v"(d) : "v"(a), "v"(b), "v"(c));
    return d;
}
__device__ __forceinline__ float dpp_up1(float x) {   // lane i <- i-1
    int r = __builtin_amdgcn_update_dpp(
        0, __builtin_bit_cast(int, x), 0x111, 0xF, 0xF, true); // row_shr:1
    return __builtin_bit_cast(float, r);
}
__device__ __forceinline__ float dpp_dn1(float x) {   // lane i <- i+1
    int r = __builtin_amdgcn_update_dpp(
        0, __builtin_bit_cast(int, x), 0x101, 0xF, 0xF, true); // row_shl:1
    return __builtin_bit_cast(float, r);
}
__device__ __forceinline__ float bpermf(int addr, float x) {
    return __builtin_bit_cast(float,
        __builtin_amdgcn_ds_bpermute(addr, __builtin_bit_cast(int, x)));
}

#define PINF (__builtin_inff())
#define NINF (-__builtin_inff())

// horizontal 3-tap min/max on a row; le/ri from strip s-1/s+1 (lane -8/+8).
// fixL/fixR: clamped-window at image cols 0/511 via identity operand.
template<bool MN>
__device__ __forceinline__ void hpool(const R8& r, R8& h, bool fixL, bool fixR,
                                      int aL, int aR) {
    const float ID = MN ? PINF : NINF;
    float le = bpermf(aL, r.v[7]);
    float ri = bpermf(aR, r.v[0]);
    float tL = fixL ? ID : r.v[3];   // left tap of col4 (gx==0: drop)
    float tR = fixR ? ID : r.v[4];   // right tap of col3 (gx==511: drop)
    if (MN) {
        h.v[0] = f3min(le,     r.v[0], r.v[1]);
        h.v[1] = f3min(r.v[0], r.v[1], r.v[2]);
        h.v[2] = f3min(r.v[1], r.v[2], r.v[3]);
        h.v[3] = f3min(r.v[2], r.v[3], tR);
        h.v[4] = f3min(tL,     r.v[4], r.v[5]);
        h.v[5] = f3min(r.v[4], r.v[5], r.v[6]);
        h.v[6] = f3min(r.v[5], r.v[6], r.v[7]);
        h.v[7] = f3min(r.v[6], r.v[7], ri);
    } else {
        h.v[0] = f3max(le,     r.v[0], r.v[1]);
        h.v[1] = f3max(r.v[0], r.v[1], r.v[2]);
        h.v[2] = f3max(r.v[1], r.v[2], r.v[3]);
        h.v[3] = f3max(r.v[2], r.v[3], tR);
        h.v[4] = f3max(tL,     r.v[4], r.v[5]);
        h.v[5] = f3max(r.v[4], r.v[5], r.v[6]);
        h.v[6] = f3max(r.v[5], r.v[6], r.v[7]);
        h.v[7] = f3max(r.v[6], r.v[7], ri);
    }
}

// horizontal 3-tap SUM (epilogue, target side, register row). Order matches
// R14 epilogue exactly: center + left + right. zL/zR: image-edge zero taps
// (exact-0 add). le/ri across strips via bpermute.
__device__ __forceinline__ R8 hrowT(const R8& r, bool zL, bool zR,
                                    int aL, int aR) {
    R8 h;
    float le = bpermf(aL, r.v[7]);
    float ri = bpermf(aR, r.v[0]);
    float L4 = zL ? 0.0f : r.v[3];
    float R3 = zR ? 0.0f : r.v[4];
    h.v[0] = r.v[0] + le     + r.v[1];
    h.v[1] = r.v[1] + r.v[0] + r.v[2];
    h.v[2] = r.v[2] + r.v[1] + r.v[3];
    h.v[3] = r.v[3] + r.v[2] + R3;
    h.v[4] = r.v[4] + L4     + r.v[5];
    h.v[5] = r.v[5] + r.v[4] + r.v[6];
    h.v[6] = r.v[6] + r.v[5] + r.v[7];
    h.v[7] = r.v[7] + r.v[6] + ri;
    return h;
}

// horizontal 3-tap SUM from a 10-float LDS row buffer rp[k] <-> col c0-1+k
// (element j: center rp[j+1], left rp[j], right rp[j+2]).
__device__ __forceinline__ R8 hrowP(const float* rp, bool zL, bool zR) {
    R8 h;
    #pragma unroll
    for (int j = 0; j < 8; ++j) {
        float L = (zL && j == 4) ? 0.0f : rp[j];
        float R = (zR && j == 3) ? 0.0f : rp[j + 2];
        h.v[j] = rp[j + 1] + L + R;
    }
    return h;
}

__global__ __launch_bounds__(NT, 3)
void skel_conn_loss(const float* __restrict__ pred,
                    const float* __restrict__ target,
                    float* __restrict__ out)
{
    __shared__ float X[2*XHALF];         // A-halo exchange dbuf (8.7 KB)
    __shared__ float SKP[SKH*SKW];       // pred skeleton stash (26.4 KB)
    __shared__ float red[4];

    const int tid  = threadIdx.x;
    const int wv   = tid >> 6;           // wave 0..3 owns rows 40w..40w+39
    const int lane = tid & 63;
    const int s    = lane >> 3;          // 8-col strip
    const int gq   = lane & 7;           // row group (5 rows); +-1 == lane+-1
    const int img  = blockIdx.x / TPI;
    const int rem  = blockIdx.x % TPI;
    const int ty0  = (rem / 13) * TH;
    const int tx0  = (rem % 13) * OC;

    const int c0  = 8*s;
    const int r0  = 40*wv + 5*gq;
    const int gx0 = tx0 - 12 + c0;
    const bool xin = (tx0 > 0) && (tx0 + 52 <= IMG);   // strip fully in-image

    const bool lB = (tx0 == 0), rB = (tx0 + OC >= IMG);
    const bool tB = (ty0 == 0), bB = (ty0 + TH == IMG);
    const bool fixL = lB && (s == 1);                // c 12 == gx 0
    const bool fixR = rB && (s == 5);                // c 43 == gx 511
    const bool vfT  = tB && (wv == 0) && (gq == 2);  // pr 12 == gy 0 (k==2)
    const bool vfB  = bB && (wv == 3) && (gq == 3);  // pr 139 == gy 511 (k==4)
    const int  sw   = 8*s + 4*(s >> 2);              // bank-swizzled exch col
    const int  aL   = ((lane - 8) & 63) * 4;         // bpermute addrs
    const int  aR   = ((lane + 8) & 63) * 4;

    R8 A[5];

    // posts rows {A0,A1} (gq==0) / {A3,A4} (gq==7) into buffer base Xb.
    #define POST01(Xb)                                                         \
        if (gq == 0) {                                                         \
            float* p_ = (Xb) + wv * XSLOT + sw;                                \
            *(float4*)p_             = *(const float4*)&A[0].v[0];             \
            *(float4*)(p_ + 4)       = *(const float4*)&A[0].v[4];             \
            *(float4*)(p_ + XR)      = *(const float4*)&A[1].v[0];             \
            *(float4*)(p_ + XR + 4)  = *(const float4*)&A[1].v[4];             \
        }
    #define POST34(Xb)                                                         \
        if (gq == 7) {                                                         \
            float* p_ = (Xb) + wv * XSLOT + 2*XR + sw;                         \
            *(float4*)p_             = *(const float4*)&A[3].v[0];             \
            *(float4*)(p_ + 4)       = *(const float4*)&A[3].v[4];             \
            *(float4*)(p_ + XR)      = *(const float4*)&A[4].v[0];             \
            *(float4*)(p_ + XR + 4)  = *(const float4*)&A[4].v[4];             \
        }

    #pragma unroll 1
    for (int t = 0; t < 2; ++t) {
        const float* __restrict__ src =
            (t ? target : pred) + (size_t)img * (IMG * IMG);

        // ---- load strip (addresses clamped; OOB values never consumed) ----
        #pragma unroll
        for (int i = 0; i < 5; ++i) {
            int gy = min(max(ty0 - 12 + r0 + i, 0), IMG - 1);
            const float* rp = src + gy * IMG;
            if (xin) {
                *(float4*)&A[i].v[0] = *(const float4*)(rp + gx0);
                *(float4*)&A[i].v[4] = *(const float4*)(rp + gx0 + 4);
            } else {
                #pragma unroll
                for (int j = 0; j < 8; ++j)
                    A[i].v[j] = rp[min(max(gx0 + j, 0), IMG - 1)];
            }
        }

        // prologue post: buffer 0. (t=1: preceded by t0-stash barrier ->
        // buf0's t0-it4 readers are drained. t=0: kernel start, trivially ok.)
        POST01(X)
        POST34(X)

        // ROTATED sweep: iteration top = barrier -> halo; posts for the NEXT
        // iteration issue mid-body (A[0],A[1] after k=1; A[3],A[4] after
        // k=4), hiding ds_write latency under k=2..4 VALU. Buffers 0,1,0,1,0.
        #pragma unroll 1
        for (int it = 0; it < 5; ++it) {
            float* Xb = X + (it & 1) * XHALF;
            float* Xn = X + ((it + 1) & 1) * XHALF;
            __syncthreads();

            // ---- vertical halo: A[-2],A[-1],A[5],A[6] ----
            R8 am2, am1, ap5, ap6;
            #pragma unroll
            for (int j = 0; j < 8; ++j) {
                am2.v[j] = dpp_up1(A[3].v[j]);   // gq-1's A[3] = my pr-2
                am1.v[j] = dpp_up1(A[4].v[j]);   // gq-1's A[4] = my pr-1
                ap5.v[j] = dpp_dn1(A[0].v[j]);   // gq+1's A[0] = my pr+5
                ap6.v[j] = dpp_dn1(A[1].v[j]);   // gq+1's A[1] = my pr+6
            }
            if (gq == 0) {
                if (wv) {
                    const float* p = Xb + (wv - 1) * XSLOT + 2*XR + sw;
                    *(float4*)&am2.v[0] = *(const float4*)p;
                    *(float4*)&am2.v[4] = *(const float4*)(p + 4);
                    *(float4*)&am1.v[0] = *(const float4*)(p + XR);
                    *(float4*)&am1.v[4] = *(const float4*)(p + XR + 4);
                } else { am2 = A[0]; am1 = A[0]; }  // tile-edge garbage margin
            }
            if (gq == 7) {
                if (wv < 3) {
                    const float* p = Xb + (wv + 1) * XSLOT + sw;
                    *(float4*)&ap5.v[0] = *(const float4*)p;
                    *(float4*)&ap5.v[4] = *(const float4*)(p + 4);
                    *(float4*)&ap6.v[0] = *(const float4*)(p + XR);
                    *(float4*)&ap6.v[4] = *(const float4*)(p + XR + 4);
                } else { ap5 = A[4]; ap6 = A[4]; }
            }

            // ---- fused sweep: rolling w-window (wA,wB,wC), update A[k] ----
            R8 vt, wA, wB, wC, pp, mx;
            #define VMIN3(d, x, y, z)                                          \
                _Pragma("unroll")                                              \
                for (int j = 0; j < 8; ++j) d.v[j] = f3min((x).v[j], (y).v[j], (z).v[j]);
            #define UPD(i, CEN)                                                \
                _Pragma("unroll")                                              \
                for (int j = 0; j < 8; ++j) {                                  \
                    float ct = mx.v[j] - (CEN).v[j];                           \
                    A[i].v[j] = fmaxf(A[i].v[j] - ct, 0.0f);                   \
                }
            VMIN3(vt, am2, am1, A[0])                     // v[-1]
            hpool<true>(vt, wA, fixL, fixR, aL, aR);      // w[-1]
            VMIN3(vt, am1, A[0], A[1])                    // v[0]
            hpool<true>(vt, wB, fixL, fixR, aL, aR);      // w[0]
            VMIN3(vt, A[0], A[1], A[2])                   // v[1]
            hpool<true>(vt, wC, fixL, fixR, aL, aR);      // w[1]
            // k=0: window (wA,wB,wC), center wB
            #pragma unroll
            for (int j = 0; j < 8; ++j) pp.v[j] = f3max(wA.v[j], wB.v[j], wC.v[j]);
            hpool<false>(pp, mx, fixL, fixR, aL, aR);
            UPD(0, wB)
            // v[2] -> wA (vfT: pr 12 drops pr 11 tap = A[1] -> +INF identity)
            #pragma unroll
            for (int j = 0; j < 8; ++j)
                vt.v[j] = f3min(vfT ? PINF : A[1].v[j], A[2].v[j], A[3].v[j]);
            hpool<true>(vt, wA, fixL, fixR, aL, aR);      // w[2]
            // k=1: window (wB,wC,wA), center wC
            #pragma unroll
            for (int j = 0; j < 8; ++j) pp.v[j] = f3max(wB.v[j], wC.v[j], wA.v[j]);
            hpool<false>(pp, mx, fixL, fixR, aL, aR);
            UPD(1, wC)
            // A[0],A[1] final for this iteration -> post for next (rotated)
            if (it < 4) { POST01(Xn) }
            VMIN3(vt, A[2], A[3], A[4])                   // v[3]
            hpool<true>(vt, wB, fixL, fixR, aL, aR);      // w[3]
            // k=2: window (wC,wA,wB), center wA; vfT drops w[1]=wC -> -INF id
            #pragma unroll
            for (int j = 0; j < 8; ++j)
                pp.v[j] = f3max(vfT ? NINF : wC.v[j], wA.v[j], wB.v[j]);
            hpool<false>(pp, mx, fixL, fixR, aL, aR);
            UPD(2, wA)
            // v[4] -> wC (vfB: pr 139 drops pr 140 tap = ap5 -> +INF id)
            #pragma unroll
            for (int j = 0; j < 8; ++j)
                vt.v[j] = f3min(A[3].v[j], A[4].v[j], vfB ? PINF : ap5.v[j]);
            hpool<true>(vt, wC, fixL, fixR, aL, aR);      // w[4]
            // k=3: window (wA,wB,wC), center wB
            #pragma unroll
            for (int j = 0; j < 8; ++j) pp.v[j] = f3max(wA.v[j], wB.v[j], wC.v[j]);
            hpool<false>(pp, mx, fixL, fixR, aL, aR);
            UPD(3, wB)
            VMIN3(vt, A[4], ap5, ap6)                     // v[5]
            hpool<true>(vt, wA, fixL, fixR, aL, aR);      // w[5]
            // k=4: window (wB,wC,wA), center wC; vfB drops w[5]=wA -> -INF id
            #pragma unroll
            for (int j = 0; j < 8; ++j)
                pp.v[j] = f3max(wB.v[j], wC.v[j], vfB ? NINF : wA.v[j]);
            hpool<false>(pp, mx, fixL, fixR, aL, aR);
            UPD(4, wC)
            // A[3],A[4] final -> post for next (rotated)
            if (it < 4) { POST34(Xn) }
            #undef VMIN3
            #undef UPD
        }

        // ---- t==0: stash pred skeleton rows [10,141] x cols [7,56] ----
        if (t == 0) {
            #pragma unroll
            for (int i = 0; i < 5; ++i) {
                int pr = r0 + i;
                if (pr >= 10 && pr <= 141) {
                    #pragma unroll
                    for (int j = 0; j < 8; ++j) {
                        int pc = c0 + j;
                        if (pc >= 7 && pc <= 56)
                            SKP[(pr - 10) * SKW + (pc - 7)] = A[i].v[j];
                    }
                }
            }
            __syncthreads();   // SKP visible; also drains buf0's it4 readers
        }
    }

    // ==== epilogue (register layout) ====
    // Uses BUF1: last readers were t1-it3, drained by barrier at top of
    // t1-it4 (t1-it4 read buf0). Posts here are therefore race-free.
    R8 am1, ap5;
    {
        float* Xb = X + XHALF;
        if (gq == 0) {   // post A[0] -> slot row 0
            float* p = Xb + wv * XSLOT + sw;
            *(float4*)p       = *(const float4*)&A[0].v[0];
            *(float4*)(p + 4) = *(const float4*)&A[0].v[4];
        }
        if (gq == 7) {   // post A[4] -> slot row 3
            float* p = Xb + wv * XSLOT + 3*XR + sw;
            *(float4*)p       = *(const float4*)&A[4].v[0];
            *(float4*)(p + 4) = *(const float4*)&A[4].v[4];
        }
        __syncthreads();
        #pragma unroll
        for (int j = 0; j < 8; ++j) {
            am1.v[j] = dpp_up1(A[4].v[j]);   // gq-1's A[4] = my pr-1
            ap5.v[j] = dpp_dn1(A[0].v[j]);   // gq+1's A[0] = my pr+5
        }
        if (gq == 0 && wv) {
            const float* p = Xb + (wv - 1) * XSLOT + 3*XR + sw;
            *(float4*)&am1.v[0] = *(const float4*)p;
            *(float4*)&am1.v[4] = *(const float4*)(p + 4);
        }
        if (gq == 7 && wv < 3) {
            const float* p = Xb + (wv + 1) * XSLOT + sw;
            *(float4*)&ap5.v[0] = *(const float4*)p;
            *(float4*)&ap5.v[4] = *(const float4*)(p + 4);
        }
        // wv==0,gq==0 / wv==3,gq==7: garbage; those rows are rok-masked.
    }

    // Pred rows from SKP: 10-float segments at col base c0-8 (8B-aligned for
    // s=1..6; clamped for garbage strips s=0/7 which have no valid cols).
    const int bc = min(max(c0 - 8, 0), SKW - 10);
    float acc = 0.0f;
    {
        auto loadrow = [&](int gpr, float* r) {
            int rr = min(max(gpr - 10, 0), SKH - 1);
            const float* p = SKP + rr * SKW + bc;
            *(float2*)&r[0] = *(const float2*)(p + 0);
            *(float2*)&r[2] = *(const float2*)(p + 2);
            *(float2*)&r[4] = *(const float2*)(p + 4);
            *(float2*)&r[6] = *(const float2*)(p + 6);
            *(float2*)&r[8] = *(const float2*)(p + 8);
        };

        float rp[10];
        loadrow(r0 - 1, rp);
        R8 hpm = hrowP(rp, fixL, fixR);      // pred hsum row pr-1
        loadrow(r0, rp);
        R8 hpc = hrowP(rp, fixL, fixR);      // pred hsum row pr
        R8 rawC;                              // pred skeleton centers, row pr
        #pragma unroll
        for (int j = 0; j < 8; ++j) rawC.v[j] = rp[j + 1];

        R8 htm = hrowT(am1,  fixL, fixR, aL, aR);   // target hsum row pr-1
        R8 htc = hrowT(A[0], fixL, fixR, aL, aR);   // target hsum row pr

        // Per output row I: n = (top + mid) + bot, exact replicate of R14's
        // hp0+hp1+hp2 left-assoc order; zero-tap at image top/bottom rows.
        #define EPI_STEP(I, TNEXT)                                             \
        {                                                                      \
            loadrow(r0 + I + 1, rp);                                           \
            R8 hpp = hrowP(rp, fixL, fixR);                                    \
            R8 htp = TNEXT;                                                    \
            const int pr_ = r0 + I;                                            \
            const bool rok = (pr_ >= 12) && (pr_ <= 139);                      \
            const bool dT = tB && (pr_ == 12);                                 \
            const bool dB = bB && (pr_ == 139);                                \
            _Pragma("unroll")                                                  \
            for (int j = 0; j < 8; ++j) {                                      \
                float pn = (dT ? 0.0f : hpm.v[j]) + hpc.v[j]                   \
                         + (dB ? 0.0f : hpp.v[j]);                             \
                float tn = (dT ? 0.0f : htm.v[j]) + htc.v[j]                   \
                         + (dB ? 0.0f : htp.v[j]);                             \
                float ps = rawC.v[j];                                          \
                float ts = A[I].v[j];                                          \
                float pon = (ps > 0.5f) ? 1.0f : 0.0f;                         \
                float ton = (ts > 0.5f) ? 1.0f : 0.0f;                         \
                float pe = (pn == 2.0f) ? pon : 0.0f;                          \
                float te = (tn == 2.0f) ? ton : 0.0f;                          \
                float pq = (pn >= 4.0f) ? pon : 0.0f;                          \
                float tq = (tn >= 4.0f) ? ton : 0.0f;                          \
                int pc_ = c0 + j;                                              \
                bool cok = (pc_ >= 12) && (pc_ <= 51) &&                       \
                           (tx0 + pc_ - 12 < IMG);                             \
                float ds = ps - ts, de = pe - te, dc = pq - tq;                \
                float e = 0.6f * ds * ds + 0.2f * (de * de + dc * dc);         \
                acc += (rok && cok) ? e : 0.0f;                                \
            }                                                                  \
            hpm = hpc; hpc = hpp; htm = htc; htc = htp;                        \
            _Pragma("unroll")                                                  \
            for (int j = 0; j < 8; ++j) rawC.v[j] = rp[j + 1];                 \
        }

        EPI_STEP(0, hrowT(A[1], fixL, fixR, aL, aR))
        EPI_STEP(1, hrowT(A[2], fixL, fixR, aL, aR))
        EPI_STEP(2, hrowT(A[3], fixL, fixR, aL, aR))
        EPI_STEP(3, hrowT(A[4], fixL, fixR, aL, aR))
        EPI_STEP(4, hrowT(ap5,  fixL, fixR, aL, aR))
        #undef EPI_STEP
    }

    // ---- block reduction -> ONE atomic per block (R9: per-wave atomics
    // serialize cross-XCD, +100us) ----
    #pragma unroll
    for (int off = 32; off >= 1; off >>= 1)
        acc += __shfl_down(acc, off, 64);
    if (lane == 0) red[wv] = acc;
    __syncthreads();
    if (tid == 0) {
        float sum = red[0] + red[1] + red[2] + red[3];
        atomicAdd(out, sum * (1.0f / 8388608.0f));  // N = 32*512*512 = 2^23
    }
}

extern "C" void kernel_launch(void* const* d_in, const int* in_sizes, int n_in,
                              void* d_out, int out_size, void* d_ws, size_t ws_size,
                              hipStream_t stream) {
    const float* pred   = (const float*)d_in[0];
    const float* target = (const float*)d_in[1];
    float* out = (float*)d_out;
    hipMemsetAsync(d_out, 0, sizeof(float) * (out_size > 0 ? out_size : 1), stream);
    const int nblocks = 32 * TPI;   // 32 images x (4x13) tiles = 1664
    skel_conn_loss<<<nblocks, NT, 0, stream>>>(pred, target, out);
}

// Round 19
// 166.343 us; speedup vs baseline: 1.0500x; 1.0500x over previous
//
#include <hip/hip_runtime.h>

// ConnectivityLoss R31 == R24 (FINAL KEEPER). Scheduling arc closed:
// R28 (branch dispatch) 39.9MB scratch/100.3us; R29 (full unroll) 20MB/
// 103.5us; R30 (post rotation) 16.7MB/102us. At 84 live VGPRs under the
// (256,3)=170-reg budget the sweep body sits exactly at the allocator's
// comfort boundary: ANY source-level reordering pressure (branch scope,
// duplication, interleaved ds_writes) tips it into scratch. The compiler's
// default schedule of THIS source is the local optimum; scheduling is not
// winnable from HIP source here.
// Config ledger (all HW-measured): (256,3)+LDS-diet = 84 VGPR, 52KB WRITE,
// 3 blk, 96.3us <- THIS. (256,4)/no-attr/waves(3,4) = 64 VGPR squeeze +
// 50MB spill, 103us. 84-VGPR+4-blk unreachable via metadata.
// Levers kept: R14 forced v_min3/v_max3 + identity-operand boundary selects
// (103.5->95.5); R15 LDS diet (no SKT; target skeleton in regs; register-
// layout epilogue; pred re-read from SKP).
// EMPIRICAL RULES: one atomic/block (R9); WRITE_SIZE ~64KB no-spill
// tripwire; no big temporaries in divergent paths (R7, reconfirmed R28);
// no sweep-body duplication/reordering (R29/R30).
// PREDICTION: reproduces round-12: VGPR 84, WRITE ~52KB, FETCH ~90MB,
// Occ ~25, dur 95.8-96.8us.

#define IMG 512
#define OC  40            // output cols per tile (13 x-tiles; last partial)
#define TH  128           // output rows per tile (4 y-tiles)
#define TPI 52            // tiles per image = 13 * 4
#define SKW 50            // pred stash cols: pc in [7,56] -> idx pc-7
#define SKH 132           // pred stash rows: pr in [10,141] -> idx pr-10
#define XR   68           // exchange row stride (floats)
#define XSLOT (4*XR)      // 4 rows per wave
#define XHALF (4*XSLOT)   // 4 waves
#define NT  256

struct alignas(16) R8 { float v[8]; };

__device__ __forceinline__ float f3min(float a, float b, float c) {
    float d;
    asm("v_min3_f32 %0, %1, %2, %3" : "=v"(d) : "v"(a), "v"(b), "v"(c));
    return d;
}
__device__ __forceinline__ float f3max(float a, float b, float c) {
    float d;
    asm("v_max3_f32 %0, %1, %2, %3" : "=v"(d) : "v"(a), "v"(b), "v"(c));
    return d;
}
__device__ __forceinline__ float dpp_up1(float x) {   // lane i <- i-1
    int r = __builtin_amdgcn_update_dpp(
        0, __builtin_bit_cast(int, x), 0x111, 0xF, 0xF, true); // row_shr:1
    return __builtin_bit_cast(float, r);
}
__device__ __forceinline__ float dpp_dn1(float x) {   // lane i <- i+1
    int r = __builtin_amdgcn_update_dpp(
        0, __builtin_bit_cast(int, x), 0x101, 0xF, 0xF, true); // row_shl:1
    return __builtin_bit_cast(float, r);
}
__device__ __forceinline__ float bpermf(int addr, float x) {
    return __builtin_bit_cast(float,
        __builtin_amdgcn_ds_bpermute(addr, __builtin_bit_cast(int, x)));
}

#define PINF (__builtin_inff())
#define NINF (-__builtin_inff())

// horizontal 3-tap min/max on a row; le/ri from strip s-1/s+1 (lane -8/+8).
// fixL/fixR: clamped-window at image cols 0/511 via identity operand.
template<bool MN>
__device__ __forceinline__ void hpool(const R8& r, R8& h, bool fixL, bool fixR,
                                      int aL, int aR) {
    const float ID = MN ? PINF : NINF;
    float le = bpermf(aL, r.v[7]);
    float ri = bpermf(aR, r.v[0]);
    float tL = fixL ? ID : r.v[3];   // left tap of col4 (gx==0: drop)
    float tR = fixR ? ID : r.v[4];   // right tap of col3 (gx==511: drop)
    if (MN) {
        h.v[0] = f3min(le,     r.v[0], r.v[1]);
        h.v[1] = f3min(r.v[0], r.v[1], r.v[2]);
        h.v[2] = f3min(r.v[1], r.v[2], r.v[3]);
        h.v[3] = f3min(r.v[2], r.v[3], tR);
        h.v[4] = f3min(tL,     r.v[4], r.v[5]);
        h.v[5] = f3min(r.v[4], r.v[5], r.v[6]);
        h.v[6] = f3min(r.v[5], r.v[6], r.v[7]);
        h.v[7] = f3min(r.v[6], r.v[7], ri);
    } else {
        h.v[0] = f3max(le,     r.v[0], r.v[1]);
        h.v[1] = f3max(r.v[0], r.v[1], r.v[2]);
        h.v[2] = f3max(r.v[1], r.v[2], r.v[3]);
        h.v[3] = f3max(r.v[2], r.v[3], tR);
        h.v[4] = f3max(tL,     r.v[4], r.v[5]);
        h.v[5] = f3max(r.v[4], r.v[5], r.v[6]);
        h.v[6] = f3max(r.v[5], r.v[6], r.v[7]);
        h.v[7] = f3max(r.v[6], r.v[7], ri);
    }
}

// horizontal 3-tap SUM (epilogue, target side, register row). Order matches
// R14 epilogue exactly: center + left + right. zL/zR: image-edge zero taps
// (exact-0 add). le/ri across strips via bpermute.
__device__ __forceinline__ R8 hrowT(const R8& r, bool zL, bool zR,
                                    int aL, int aR) {
    R8 h;
    float le = bpermf(aL, r.v[7]);
    float ri = bpermf(aR, r.v[0]);
    float L4 = zL ? 0.0f : r.v[3];
    float R3 = zR ? 0.0f : r.v[4];
    h.v[0] = r.v[0] + le     + r.v[1];
    h.v[1] = r.v[1] + r.v[0] + r.v[2];
    h.v[2] = r.v[2] + r.v[1] + r.v[3];
    h.v[3] = r.v[3] + r.v[2] + R3;
    h.v[4] = r.v[4] + L4     + r.v[5];
    h.v[5] = r.v[5] + r.v[4] + r.v[6];
    h.v[6] = r.v[6] + r.v[5] + r.v[7];
    h.v[7] = r.v[7] + r.v[6] + ri;
    return h;
}

// horizontal 3-tap SUM from a 10-float LDS row buffer rp[k] <-> col c0-1+k
// (element j: center rp[j+1], left rp[j], right rp[j+2]).
__device__ __forceinline__ R8 hrowP(const float* rp, bool zL, bool zR) {
    R8 h;
    #pragma unroll
    for (int j = 0; j < 8; ++j) {
        float L = (zL && j == 4) ? 0.0f : rp[j];
        float R = (zR && j == 3) ? 0.0f : rp[j + 2];
        h.v[j] = rp[j + 1] + L + R;
    }
    return h;
}

__global__ __launch_bounds__(NT, 3)
void skel_conn_loss(const float* __restrict__ pred,
                    const float* __restrict__ target,
                    float* __restrict__ out)
{
    __shared__ float X[2*XHALF];         // A-halo exchange dbuf (8.7 KB)
    __shared__ float SKP[SKH*SKW];       // pred skeleton stash (26.4 KB)
    __shared__ float red[4];

    const int tid  = threadIdx.x;
    const int wv   = tid >> 6;           // wave 0..3 owns rows 40w..40w+39
    const int lane = tid & 63;
    const int s    = lane >> 3;          // 8-col strip
    const int gq   = lane & 7;           // row group (5 rows); +-1 == lane+-1
    const int img  = blockIdx.x / TPI;
    const int rem  = blockIdx.x % TPI;
    const int ty0  = (rem / 13) * TH;
    const int tx0  = (rem % 13) * OC;

    const int c0  = 8*s;
    const int r0  = 40*wv + 5*gq;
    const int gx0 = tx0 - 12 + c0;
    const bool xin = (tx0 > 0) && (tx0 + 52 <= IMG);   // strip fully in-image

    const bool lB = (tx0 == 0), rB = (tx0 + OC >= IMG);
    const bool tB = (ty0 == 0), bB = (ty0 + TH == IMG);
    const bool fixL = lB && (s == 1);                // c 12 == gx 0
    const bool fixR = rB && (s == 5);                // c 43 == gx 511
    const bool vfT  = tB && (wv == 0) && (gq == 2);  // pr 12 == gy 0 (k==2)
    const bool vfB  = bB && (wv == 3) && (gq == 3);  // pr 139 == gy 511 (k==4)
    const int  sw   = 8*s + 4*(s >> 2);              // bank-swizzled exch col
    const int  aL   = ((lane - 8) & 63) * 4;         // bpermute addrs
    const int  aR   = ((lane + 8) & 63) * 4;

    R8 A[5];
    int xb = 0;

    #pragma unroll 1
    for (int t = 0; t < 2; ++t) {
        const float* __restrict__ src =
            (t ? target : pred) + (size_t)img * (IMG * IMG);

        // ---- load strip (addresses clamped; OOB values never consumed) ----
        #pragma unroll
        for (int i = 0; i < 5; ++i) {
            int gy = min(max(ty0 - 12 + r0 + i, 0), IMG - 1);
            const float* rp = src + gy * IMG;
            if (xin) {
                *(float4*)&A[i].v[0] = *(const float4*)(rp + gx0);
                *(float4*)&A[i].v[4] = *(const float4*)(rp + gx0 + 4);
            } else {
                #pragma unroll
                for (int j = 0; j < 8; ++j)
                    A[i].v[j] = rp[min(max(gx0 + j, 0), IMG - 1)];
            }
        }

        #pragma unroll 1
        for (int it = 0; it < 5; ++it) {
            float* Xb = X + xb * XHALF;
            // ---- post boundary A-rows (old values) for vertical halo ----
            if (gq == 0) {
                float* p = Xb + wv * XSLOT + sw;          // rows 0,1
                *(float4*)p            = *(const float4*)&A[0].v[0];
                *(float4*)(p + 4)      = *(const float4*)&A[0].v[4];
                *(float4*)(p + XR)     = *(const float4*)&A[1].v[0];
                *(float4*)(p + XR + 4) = *(const float4*)&A[1].v[4];
            }
            if (gq == 7) {
                float* p = Xb + wv * XSLOT + 2*XR + sw;   // rows 2,3
                *(float4*)p            = *(const float4*)&A[3].v[0];
                *(float4*)(p + 4)      = *(const float4*)&A[3].v[4];
                *(float4*)(p + XR)     = *(const float4*)&A[4].v[0];
                *(float4*)(p + XR + 4) = *(const float4*)&A[4].v[4];
            }
            __syncthreads();

            // ---- vertical halo: A[-2],A[-1],A[5],A[6] ----
            R8 am2, am1, ap5, ap6;
            #pragma unroll
            for (int j = 0; j < 8; ++j) {
                am2.v[j] = dpp_up1(A[3].v[j]);   // gq-1's A[3] = my pr-2
                am1.v[j] = dpp_up1(A[4].v[j]);   // gq-1's A[4] = my pr-1
                ap5.v[j] = dpp_dn1(A[0].v[j]);   // gq+1's A[0] = my pr+5
                ap6.v[j] = dpp_dn1(A[1].v[j]);   // gq+1's A[1] = my pr+6
            }
            if (gq == 0) {
                if (wv) {
                    const float* p = Xb + (wv - 1) * XSLOT + 2*XR + sw;
                    *(float4*)&am2.v[0] = *(const float4*)p;
                    *(float4*)&am2.v[4] = *(const float4*)(p + 4);
                    *(float4*)&am1.v[0] = *(const float4*)(p + XR);
                    *(float4*)&am1.v[4] = *(const float4*)(p + XR + 4);
                } else { am2 = A[0]; am1 = A[0]; }  // tile-edge garbage margin
            }
            if (gq == 7) {
                if (wv < 3) {
                    const float* p = Xb + (wv + 1) * XSLOT + sw;
                    *(float4*)&ap5.v[0] = *(const float4*)p;
                    *(float4*)&ap5.v[4] = *(const float4*)(p + 4);
                    *(float4*)&ap6.v[0] = *(const float4*)(p + XR);
                    *(float4*)&ap6.v[4] = *(const float4*)(p + XR + 4);
                } else { ap5 = A[4]; ap6 = A[4]; }
            }

            // ---- fused sweep: rolling w-window (wA,wB,wC), update A[k] ----
            R8 vt, wA, wB, wC, pp, mx;
            #define VMIN3(d, x, y, z)                                          \
                _Pragma("unroll")                                              \
                for (int j = 0; j < 8; ++j) d.v[j] = f3min((x).v[j], (y).v[j], (z).v[j]);
            #define UPD(i, CEN)                                                \
                _Pragma("unroll")                                              \
                for (int j = 0; j < 8; ++j) {                                  \
                    float ct = mx.v[j] - (CEN).v[j];                           \
                    A[i].v[j] = fmaxf(A[i].v[j] - ct, 0.0f);                   \
                }
            VMIN3(vt, am2, am1, A[0])                     // v[-1]
            hpool<true>(vt, wA, fixL, fixR, aL, aR);      // w[-1]
            VMIN3(vt, am1, A[0], A[1])                    // v[0]
            hpool<true>(vt, wB, fixL, fixR, aL, aR);      // w[0]
            VMIN3(vt, A[0], A[1], A[2])                   // v[1]
            hpool<true>(vt, wC, fixL, fixR, aL, aR);      // w[1]
            // k=0: window (wA,wB,wC), center wB
            #pragma unroll
            for (int j = 0; j < 8; ++j) pp.v[j] = f3max(wA.v[j], wB.v[j], wC.v[j]);
            hpool<false>(pp, mx, fixL, fixR, aL, aR);
            UPD(0, wB)
            // v[2] -> wA (vfT: pr 12 drops pr 11 tap = A[1] -> +INF identity)
            #pragma unroll
            for (int j = 0; j < 8; ++j)
                vt.v[j] = f3min(vfT ? PINF : A[1].v[j], A[2].v[j], A[3].v[j]);
            hpool<true>(vt, wA, fixL, fixR, aL, aR);      // w[2]
            // k=1: window (wB,wC,wA), center wC
            #pragma unroll
            for (int j = 0; j < 8; ++j) pp.v[j] = f3max(wB.v[j], wC.v[j], wA.v[j]);
            hpool<false>(pp, mx, fixL, fixR, aL, aR);
            UPD(1, wC)
            VMIN3(vt, A[2], A[3], A[4])                   // v[3]
            hpool<true>(vt, wB, fixL, fixR, aL, aR);      // w[3]
            // k=2: window (wC,wA,wB), center wA; vfT drops w[1]=wC -> -INF id
            #pragma unroll
            for (int j = 0; j < 8; ++j)
                pp.v[j] = f3max(vfT ? NINF : wC.v[j], wA.v[j], wB.v[j]);
            hpool<false>(pp, mx, fixL, fixR, aL, aR);
            UPD(2, wA)
            // v[4] -> wC (vfB: pr 139 drops pr 140 tap = ap5 -> +INF id)
            #pragma unroll
            for (int j = 0; j < 8; ++j)
                vt.v[j] = f3min(A[3].v[j], A[4].v[j], vfB ? PINF : ap5.v[j]);
            hpool<true>(vt, wC, fixL, fixR, aL, aR);      // w[4]
            // k=3: window (wA,wB,wC), center wB
            #pragma unroll
            for (int j = 0; j < 8; ++j) pp.v[j] = f3max(wA.v[j], wB.v[j], wC.v[j]);
            hpool<false>(pp, mx, fixL, fixR, aL, aR);
            UPD(3, wB)
            VMIN3(vt, A[4], ap5, ap6)                     // v[5]
            hpool<true>(vt, wA, fixL, fixR, aL, aR);      // w[5]
            // k=4: window (wB,wC,wA), center wC; vfB drops w[5]=wA -> -INF id
            #pragma unroll
            for (int j = 0; j < 8; ++j)
                pp.v[j] = f3max(wB.v[j], wC.v[j], vfB ? NINF : wA.v[j]);
            hpool<false>(pp, mx, fixL, fixR, aL, aR);
            UPD(4, wC)
            #undef VMIN3
            #undef UPD
            xb ^= 1;
        }

        // ---- t==0: stash pred skeleton rows [10,141] x cols [7,56] ----
        if (t == 0) {
            #pragma unroll
            for (int i = 0; i < 5; ++i) {
                int pr = r0 + i;
                if (pr >= 10 && pr <= 141) {
                    #pragma unroll
                    for (int j = 0; j < 8; ++j) {
                        int pc = c0 + j;
                        if (pc >= 7 && pc <= 56)
                            SKP[(pr - 10) * SKW + (pc - 7)] = A[i].v[j];
                    }
                }
            }
            __syncthreads();   // SKP visible to all; X dbuf chain continues
        }
    }

    // ==== epilogue (register layout) ====
    // Target skeleton is in A[0..4] (rows pr=r0..r0+4). Pred skeleton in SKP.
    // Vertical halo rows (pr-1, pr+5) for the target: dpp + one X exchange.
    R8 am1, ap5;
    {
        float* Xb = X;   // buffer 0: last readers were t1-it3, drained by
                         // barrier inside t1-it4 (writer is past it). Safe.
        if (gq == 0) {   // post A[0] -> slot row 0
            float* p = Xb + wv * XSLOT + sw;
            *(float4*)p       = *(const float4*)&A[0].v[0];
            *(float4*)(p + 4) = *(const float4*)&A[0].v[4];
        }
        if (gq == 7) {   // post A[4] -> slot row 3
            float* p = Xb + wv * XSLOT + 3*XR + sw;
            *(float4*)p       = *(const float4*)&A[4].v[0];
            *(float4*)(p + 4) = *(const float4*)&A[4].v[4];
        }
        __syncthreads();
        #pragma unroll
        for (int j = 0; j < 8; ++j) {
            am1.v[j] = dpp_up1(A[4].v[j]);   // gq-1's A[4] = my pr-1
            ap5.v[j] = dpp_dn1(A[0].v[j]);   // gq+1's A[0] = my pr+5
        }
        if (gq == 0 && wv) {
            const float* p = Xb + (wv - 1) * XSLOT + 3*XR + sw;
            *(float4*)&am1.v[0] = *(const float4*)p;
            *(float4*)&am1.v[4] = *(const float4*)(p + 4);
        }
        if (gq == 7 && wv < 3) {
            const float* p = Xb + (wv + 1) * XSLOT + sw;
            *(float4*)&ap5.v[0] = *(const float4*)p;
            *(float4*)&ap5.v[4] = *(const float4*)(p + 4);
        }
        // wv==0,gq==0 / wv==3,gq==7: garbage; those rows are rok-masked.
    }

    // Pred rows from SKP: 10-float segments at col base c0-8 (8B-aligned for
    // s=1..6; clamped for garbage strips s=0/7 which have no valid cols).
    const int bc = min(max(c0 - 8, 0), SKW - 10);
    float acc = 0.0f;
    {
        auto loadrow = [&](int gpr, float* r) {
            int rr = min(max(gpr - 10, 0), SKH - 1);
            const float* p = SKP + rr * SKW + bc;
            *(float2*)&r[0] = *(const float2*)(p + 0);
            *(float2*)&r[2] = *(const float2*)(p + 2);
            *(float2*)&r[4] = *(const float2*)(p + 4);
            *(float2*)&r[6] = *(const float2*)(p + 6);
            *(float2*)&r[8] = *(const float2*)(p + 8);
        };

        float rp[10];
        loadrow(r0 - 1, rp);
        R8 hpm = hrowP(rp, fixL, fixR);      // pred hsum row pr-1
        loadrow(r0, rp);
        R8 hpc = hrowP(rp, fixL, fixR);      // pred hsum row pr
        R8 rawC;                              // pred skeleton centers, row pr
        #pragma unroll
        for (int j = 0; j < 8; ++j) rawC.v[j] = rp[j + 1];

        R8 htm = hrowT(am1,  fixL, fixR, aL, aR);   // target hsum row pr-1
        R8 htc = hrowT(A[0], fixL, fixR, aL, aR);   // target hsum row pr

        // Per output row I: n = (top + mid) + bot, exact replicate of R14's
        // hp0+hp1+hp2 left-assoc order; zero-tap at image top/bottom rows.
        #define EPI_STEP(I, TNEXT)                                             \
        {                                                                      \
            loadrow(r0 + I + 1, rp);                                           \
            R8 hpp = hrowP(rp, fixL, fixR);                                    \
            R8 htp = TNEXT;                                                    \
            const int pr_ = r0 + I;                                            \
            const bool rok = (pr_ >= 12) && (pr_ <= 139);                      \
            const bool dT = tB && (pr_ == 12);                                 \
            const bool dB = bB && (pr_ == 139);                                \
            _Pragma("unroll")                                                  \
            for (int j = 0; j < 8; ++j) {                                      \
                float pn = (dT ? 0.0f : hpm.v[j]) + hpc.v[j]                   \
                         + (dB ? 0.0f : hpp.v[j]);                             \
                float tn = (dT ? 0.0f : htm.v[j]) + htc.v[j]                   \
                         + (dB ? 0.0f : htp.v[j]);                             \
                float ps = rawC.v[j];                                          \
                float ts = A[I].v[j];                                          \
                float pon = (ps > 0.5f) ? 1.0f : 0.0f;                         \
                float ton = (ts > 0.5f) ? 1.0f : 0.0f;                         \
                float pe = (pn == 2.0f) ? pon : 0.0f;                          \
                float te = (tn == 2.0f) ? ton : 0.0f;                          \
                float pq = (pn >= 4.0f) ? pon : 0.0f;                          \
                float tq = (tn >= 4.0f) ? ton : 0.0f;                          \
                int pc_ = c0 + j;                                              \
                bool cok = (pc_ >= 12) && (pc_ <= 51) &&                       \
                           (tx0 + pc_ - 12 < IMG);                             \
                float ds = ps - ts, de = pe - te, dc = pq - tq;                \
                float e = 0.6f * ds * ds + 0.2f * (de * de + dc * dc);         \
                acc += (rok && cok) ? e : 0.0f;                                \
            }                                                                  \
            hpm = hpc; hpc = hpp; htm = htc; htc = htp;                        \
            _Pragma("unroll")                                                  \
            for (int j = 0; j < 8; ++j) rawC.v[j] = rp[j + 1];                 \
        }

        EPI_STEP(0, hrowT(A[1], fixL, fixR, aL, aR))
        EPI_STEP(1, hrowT(A[2], fixL, fixR, aL, aR))
        EPI_STEP(2, hrowT(A[3], fixL, fixR, aL, aR))
        EPI_STEP(3, hrowT(A[4], fixL, fixR, aL, aR))
        EPI_STEP(4, hrowT(ap5,  fixL, fixR, aL, aR))
        #undef EPI_STEP
    }

    // ---- block reduction -> ONE atomic per block (R9: per-wave atomics
    // serialize cross-XCD, +100us) ----
    #pragma unroll
    for (int off = 32; off >= 1; off >>= 1)
        acc += __shfl_down(acc, off, 64);
    if (lane == 0) red[wv] = acc;
    __syncthreads();
    if (tid == 0) {
        float sum = red[0] + red[1] + red[2] + red[3];
        atomicAdd(out, sum * (1.0f / 8388608.0f));  // N = 32*512*512 = 2^23
    }
}

extern "C" void kernel_launch(void* const* d_in, const int* in_sizes, int n_in,
                              void* d_out, int out_size, void* d_ws, size_t ws_size,
                              hipStream_t stream) {
    const float* pred   = (const float*)d_in[0];
    const float* target = (const float*)d_in[1];
    float* out = (float*)d_out;
    hipMemsetAsync(d_out, 0, sizeof(float) * (out_size > 0 ? out_size : 1), stream);
    const int nblocks = 32 * TPI;   // 32 images x (4x13) tiles = 1664
    skel_conn_loss<<<nblocks, NT, 0, stream>>>(pred, target, out);
}